// Round 1
// baseline (1481.598 us; speedup 1.0000x reference)
//
#include <hip/hip_runtime.h>
#include <cmath>

static constexpr int Bb = 4, Ss = 1024, Ee = 768, Hh = 8, HDd = 96;
static constexpr int BS = Bb * Ss;  // 4096 rows

// ---------------- generic tiled fp32 GEMM: C = act(A[M,K] @ W[K,N] + bias[N]) ----------------
// 64x64 tile, BK=16, 256 threads, 4x4 per thread. All dims here divide evenly.
template <int RELU>
__global__ __launch_bounds__(256) void gemm_bias_k(
    const float* __restrict__ A, const float* __restrict__ W,
    const float* __restrict__ bias, float* __restrict__ C,
    int M, int N, int K)
{
    __shared__ float As[16][65];
    __shared__ float Ws[16][65];
    const int t  = threadIdx.x;
    const int tx = t & 15, ty = t >> 4;
    const int bm = blockIdx.y, bn = blockIdx.x;

    const int arow = t >> 2;         // 0..63
    const int ak0  = (t & 3) << 2;   // 0,4,8,12
    const int wrow = t >> 4;         // 0..15
    const int wc0  = (t & 15) << 2;  // 0..60

    const float* Aptr = A + (size_t)(bm * 64 + arow) * K + ak0;
    const float* Wptr = W + (size_t)wrow * N + (size_t)bn * 64 + wc0;

    float acc[4][4] = {};

    for (int k0 = 0; k0 < K; k0 += 16) {
        const float4 av = *reinterpret_cast<const float4*>(Aptr + k0);
        const float4 wv = *reinterpret_cast<const float4*>(Wptr + (size_t)k0 * N);
        __syncthreads();
        As[ak0 + 0][arow] = av.x;
        As[ak0 + 1][arow] = av.y;
        As[ak0 + 2][arow] = av.z;
        As[ak0 + 3][arow] = av.w;
        Ws[wrow][wc0 + 0] = wv.x;
        Ws[wrow][wc0 + 1] = wv.y;
        Ws[wrow][wc0 + 2] = wv.z;
        Ws[wrow][wc0 + 3] = wv.w;
        __syncthreads();
#pragma unroll
        for (int kk = 0; kk < 16; ++kk) {
            float a[4], w[4];
#pragma unroll
            for (int i = 0; i < 4; ++i) a[i] = As[kk][ty + 16 * i];
#pragma unroll
            for (int j = 0; j < 4; ++j) w[j] = Ws[kk][tx + 16 * j];
#pragma unroll
            for (int i = 0; i < 4; ++i)
#pragma unroll
                for (int j = 0; j < 4; ++j)
                    acc[i][j] = fmaf(a[i], w[j], acc[i][j]);
        }
    }

#pragma unroll
    for (int i = 0; i < 4; ++i) {
        const int row = bm * 64 + ty + 16 * i;
#pragma unroll
        for (int j = 0; j < 4; ++j) {
            const int col = bn * 64 + tx + 16 * j;
            float val = acc[i][j] + bias[col];
            if (RELU) val = fmaxf(val, 0.f);
            C[(size_t)row * N + col] = val;
        }
    }
}

// ---------------- attention over the BATCH axis (torch MHA batch_first=False quirk) -------------
// one thread per (s,h): 4x4 score matrix over batch, softmax over c, weighted V sum.
// NOTE: ao may alias q (each thread reads only its own q slice before writing its ao slice).
__global__ __launch_bounds__(256) void attn_batch_k(
    const float* q, const float* __restrict__ k,
    const float* __restrict__ v, float* ao)
{
    const int idx = blockIdx.x * 256 + threadIdx.x;
    if (idx >= Ss * Hh) return;
    const int s = idx / Hh, h = idx - s * Hh;
    const size_t base    = (size_t)s * Ee + (size_t)h * HDd;
    const size_t bstride = (size_t)Ss * Ee;

    float sc[4][4] = {};
    for (int d = 0; d < HDd; ++d) {
        float qq[4], kk4[4];
#pragma unroll
        for (int b = 0; b < 4; ++b) qq[b] = q[b * bstride + base + d];
#pragma unroll
        for (int c = 0; c < 4; ++c) kk4[c] = k[c * bstride + base + d];
#pragma unroll
        for (int b = 0; b < 4; ++b)
#pragma unroll
            for (int c = 0; c < 4; ++c)
                sc[b][c] = fmaf(qq[b], kk4[c], sc[b][c]);
    }
    const float scale = 0.10206207261596577f;  // 1/sqrt(96)
    float at[4][4];
#pragma unroll
    for (int b = 0; b < 4; ++b) {
        float mx = sc[b][0];
#pragma unroll
        for (int c = 1; c < 4; ++c) mx = fmaxf(mx, sc[b][c]);
        float sum = 0.f;
#pragma unroll
        for (int c = 0; c < 4; ++c) { at[b][c] = expf((sc[b][c] - mx) * scale); sum += at[b][c]; }
        const float inv = 1.f / sum;
#pragma unroll
        for (int c = 0; c < 4; ++c) at[b][c] *= inv;
    }
    for (int d = 0; d < HDd; ++d) {
        float vv[4];
#pragma unroll
        for (int c = 0; c < 4; ++c) vv[c] = v[c * bstride + base + d];
#pragma unroll
        for (int b = 0; b < 4; ++b) {
            float o = 0.f;
#pragma unroll
            for (int c = 0; c < 4; ++c) o = fmaf(at[b][c], vv[c], o);
            ao[b * bstride + base + d] = o;
        }
    }
}

// ---------------- probs = m1[BS,384] @ w2[384,1] + b2 : one wave per row ----------------
__global__ __launch_bounds__(256) void mlp2_probs_k(
    const float* __restrict__ m1, const float* __restrict__ w2,
    const float* __restrict__ b2, float* __restrict__ probs)
{
    const int gid  = blockIdx.x * 256 + threadIdx.x;
    const int row  = gid >> 6, lane = gid & 63;
    if (row >= BS) return;
    float acc = 0.f;
    for (int kk = lane; kk < 384; kk += 64)
        acc = fmaf(m1[(size_t)row * 384 + kk], w2[kk], acc);
#pragma unroll
    for (int off = 32; off > 0; off >>= 1) acc += __shfl_down(acc, off, 64);
    if (lane == 0) probs[row] = acc + b2[0];
}

// ---------------- ba = r1[BS,384] @ w2[384,3] + b2 : one wave per row ----------------
__global__ __launch_bounds__(256) void rb2_ba_k(
    const float* __restrict__ r1, const float* __restrict__ w2,
    const float* __restrict__ b2, float* __restrict__ ba)
{
    const int gid  = blockIdx.x * 256 + threadIdx.x;
    const int row  = gid >> 6, lane = gid & 63;
    if (row >= BS) return;
    float a0 = 0.f, a1 = 0.f, a2 = 0.f;
    for (int kk = lane; kk < 384; kk += 64) {
        const float r = r1[(size_t)row * 384 + kk];
        a0 = fmaf(r, w2[kk * 3 + 0], a0);
        a1 = fmaf(r, w2[kk * 3 + 1], a1);
        a2 = fmaf(r, w2[kk * 3 + 2], a2);
    }
#pragma unroll
    for (int off = 32; off > 0; off >>= 1) {
        a0 += __shfl_down(a0, off, 64);
        a1 += __shfl_down(a1, off, 64);
        a2 += __shfl_down(a2, off, 64);
    }
    if (lane == 0) {
        ba[(size_t)row * 3 + 0] = a0 + b2[0];
        ba[(size_t)row * 3 + 1] = a1 + b2[1];
        ba[(size_t)row * 3 + 2] = a2 + b2[2];
    }
}

// ---------------- contacts[b,i,j] = probs[b,i] (float4 fill) ----------------
__global__ __launch_bounds__(256) void contacts_k(
    const float* __restrict__ probs, float* __restrict__ out)
{
    const int f4 = blockIdx.x * 256 + threadIdx.x;  // 1048576 float4s
    if (f4 >= (Bb * Ss * Ss) / 4) return;
    const int row = f4 >> 8;  // 256 float4 per (b,i) row
    const float p = probs[row];
    reinterpret_cast<float4*>(out)[f4] = make_float4(p, p, p, p);
}

// ---------------- steps + inclusive cumsum (Hillis-Steele), one block per b ----------------
__global__ __launch_bounds__(1024) void steps_cumsum_k(
    const float* __restrict__ ba, float* __restrict__ s0)
{
    const int b = blockIdx.x;
    const int i = threadIdx.x;  // 0..1023
    const int row = b * Ss + i;
    const float phi = ba[(size_t)row * 3 + 0];
    const float psi = ba[(size_t)row * 3 + 1];
    const float cpsi = cosf(psi);
    float x = 3.8f * cosf(phi) * cpsi;
    float y = 3.8f * sinf(phi) * cpsi;
    float z = 3.8f * sinf(psi);
    if (i == 0) { x = 0.f; y = 0.f; z = 0.f; }
    __shared__ float sx[1024], sy[1024], sz[1024];
    sx[i] = x; sy[i] = y; sz[i] = z;
    for (int off = 1; off < 1024; off <<= 1) {
        __syncthreads();
        float ax = 0.f, ay = 0.f, az = 0.f;
        if (i >= off) { ax = sx[i - off]; ay = sy[i - off]; az = sz[i - off]; }
        __syncthreads();
        sx[i] += ax; sy[i] += ay; sz[i] += az;
    }
    s0[(size_t)row * 3 + 0] = sx[i];
    s0[(size_t)row * 3 + 1] = sy[i];
    s0[(size_t)row * 3 + 2] = sz[i];
}

// ---------------- one Adam step: grad of contact loss + parameter update ----------------
// grad_i = (1/N) * sum_j sign(d_ij-8) * (p_i + p_j) * (s_i - s_j) / d_ij   (d2==0 -> 0)
// one wave per (b,i) row; ping-pong s buffers (s_in read-only, s_out written).
__global__ __launch_bounds__(256) void adam_step_k(
    const float* __restrict__ sin_, float* __restrict__ sout,
    float* __restrict__ mbuf, float* __restrict__ vbuf,
    const float* __restrict__ probs, float bc1inv, float bc2inv)
{
    const int gid  = blockIdx.x * 256 + threadIdx.x;
    const int row  = gid >> 6, lane = gid & 63;
    if (row >= BS) return;
    const int jbase = (row >> 10) << 10;  // b * 1024
    const float pi_ = probs[row];
    const float sx = sin_[(size_t)row * 3 + 0];
    const float sy = sin_[(size_t)row * 3 + 1];
    const float sz = sin_[(size_t)row * 3 + 2];
    float gx = 0.f, gy = 0.f, gz = 0.f;
    for (int j = lane; j < Ss; j += 64) {
        const int jd = jbase + j;
        const float tx = sin_[(size_t)jd * 3 + 0];
        const float ty = sin_[(size_t)jd * 3 + 1];
        const float tz = sin_[(size_t)jd * 3 + 2];
        const float dx = sx - tx, dy = sy - ty, dz = sz - tz;
        const float d2 = dx * dx + dy * dy + dz * dz;
        if (d2 > 0.f) {
            const float d  = sqrtf(d2);
            const float sg = (d > 8.f) ? 1.f : -1.f;
            const float w  = sg * (pi_ + probs[jd]) / d;
            gx = fmaf(w, dx, gx);
            gy = fmaf(w, dy, gy);
            gz = fmaf(w, dz, gz);
        }
    }
#pragma unroll
    for (int off = 32; off > 0; off >>= 1) {
        gx += __shfl_down(gx, off, 64);
        gy += __shfl_down(gy, off, 64);
        gz += __shfl_down(gz, off, 64);
    }
    if (lane == 0) {
        const float invN = 1.f / 4194304.f;  // B*S*S
        float g[3] = { gx * invN, gy * invN, gz * invN };
        float scur[3] = { sx, sy, sz };
#pragma unroll
        for (int dI = 0; dI < 3; ++dI) {
            const size_t o = (size_t)row * 3 + dI;
            const float m = 0.9f * mbuf[o] + 0.1f * g[dI];
            const float v = 0.999f * vbuf[o] + 0.001f * g[dI] * g[dI];
            mbuf[o] = m; vbuf[o] = v;
            sout[o] = scur[dI] - 0.01f * (m * bc1inv) / (sqrtf(v * bc2inv) + 1e-8f);
        }
    }
}

extern "C" void kernel_launch(void* const* d_in, const int* in_sizes, int n_in,
                              void* d_out, int out_size, void* d_ws, size_t ws_size,
                              hipStream_t stream)
{
    const float* x     = (const float*)d_in[0];
    const float* bb_w1 = (const float*)d_in[1];
    const float* bb_b1 = (const float*)d_in[2];
    const float* bb_w2 = (const float*)d_in[3];
    const float* bb_b2 = (const float*)d_in[4];
    const float* sc_w1 = (const float*)d_in[5];
    const float* sc_b1 = (const float*)d_in[6];
    const float* sc_w2 = (const float*)d_in[7];
    const float* sc_b2 = (const float*)d_in[8];
    const float* wq = (const float*)d_in[9];  const float* bq = (const float*)d_in[10];
    const float* wk = (const float*)d_in[11]; const float* bk = (const float*)d_in[12];
    const float* wv = (const float*)d_in[13]; const float* bv = (const float*)d_in[14];
    const float* wo = (const float*)d_in[15]; const float* bo = (const float*)d_in[16];
    const float* mlp_w1 = (const float*)d_in[17]; const float* mlp_b1 = (const float*)d_in[18];
    const float* mlp_w2 = (const float*)d_in[19]; const float* mlp_b2 = (const float*)d_in[20];
    const float* rb_w1 = (const float*)d_in[21]; const float* rb_b1 = (const float*)d_in[22];
    const float* rb_w2 = (const float*)d_in[23]; const float* rb_b2 = (const float*)d_in[24];
    // rs_* (25..28) are dead in the reference (sa computed then deleted) -> skipped.

    float* out_backbone = (float*)d_out;                                  // [4096,768]
    float* out_side     = out_backbone + (size_t)BS * Ee;                 // [4096,768]
    float* out_contacts = out_side + (size_t)BS * Ee;                     // [4,1024,1024]
    float* out_struct   = out_contacts + (size_t)Bb * Ss * Ss;            // [4096,3]

    // workspace layout (floats). ws0: h1/s1/m1/r1 (sequential reuse);
    // ws1: q then ao (in-thread-safe alias); ws2: k then ao2; v lives in the
    // contacts output region (written later). Total need ~36.2 MB.
    float* w = (float*)d_ws;
    const size_t SLOT = (size_t)BS * Ee;  // 3,145,728 floats
    float* ws0 = w;
    float* ws1 = w + SLOT;
    float* ws2 = w + 2 * SLOT;
    float* vbufq = out_contacts;          // scratch V, overwritten by contacts later
    float* probs = w + 3 * SLOT;          // 4096
    float* ba    = probs + BS;            // 12288
    float* sA    = ba + 3 * BS;
    float* sB    = sA + 3 * BS;
    float* mB    = sB + 3 * BS;
    float* vB    = mB + 3 * BS;

    const dim3 blk(256);
    const dim3 gE(Ee / 64, BS / 64);     // N=768 tiles
    const dim3 gH(384 / 64, BS / 64);    // N=384 tiles

    // backbone / side feature networks
    gemm_bias_k<1><<<gE, blk, 0, stream>>>(x, bb_w1, bb_b1, ws0, BS, Ee, Ee);
    gemm_bias_k<0><<<gE, blk, 0, stream>>>(ws0, bb_w2, bb_b2, out_backbone, BS, Ee, Ee);
    gemm_bias_k<1><<<gH, blk, 0, stream>>>(out_backbone, sc_w1, sc_b1, ws0, BS, 384, Ee);
    gemm_bias_k<0><<<gE, blk, 0, stream>>>(ws0, sc_w2, sc_b2, out_side, BS, Ee, 384);

    // contact predictor: qkv projections, batch-axis attention, out proj, MLP
    gemm_bias_k<0><<<gE, blk, 0, stream>>>(x, wq, bq, ws1, BS, Ee, Ee);
    gemm_bias_k<0><<<gE, blk, 0, stream>>>(x, wk, bk, ws2, BS, Ee, Ee);
    gemm_bias_k<0><<<gE, blk, 0, stream>>>(x, wv, bv, vbufq, BS, Ee, Ee);
    attn_batch_k<<<dim3((Ss * Hh) / 256), blk, 0, stream>>>(ws1, ws2, vbufq, ws1);
    gemm_bias_k<0><<<gE, blk, 0, stream>>>(ws1, wo, bo, ws2, BS, Ee, Ee);
    gemm_bias_k<1><<<gH, blk, 0, stream>>>(ws2, mlp_w1, mlp_b1, ws0, BS, 384, Ee);
    mlp2_probs_k<<<dim3(BS * 64 / 256), blk, 0, stream>>>(ws0, mlp_w2, mlp_b2, probs);
    contacts_k<<<dim3(Bb * Ss * Ss / 4 / 256), blk, 0, stream>>>(probs, out_contacts);

    // structure refiner init
    gemm_bias_k<1><<<gH, blk, 0, stream>>>(out_backbone, rb_w1, rb_b1, ws0, BS, 384, Ee);
    rb2_ba_k<<<dim3(BS * 64 / 256), blk, 0, stream>>>(ws0, rb_w2, rb_b2, ba);
    steps_cumsum_k<<<dim3(Bb), dim3(1024), 0, stream>>>(ba, sA);

    // 50 Adam steps on the pairwise-distance contact loss (ping-pong s buffers)
    hipMemsetAsync(mB, 0, (size_t)2 * 3 * BS * sizeof(float), stream);
    for (int t = 1; t <= 50; ++t) {
        const float bc1inv = (float)(1.0 / (1.0 - std::pow(0.9, (double)t)));
        const float bc2inv = (float)(1.0 / (1.0 - std::pow(0.999, (double)t)));
        const float* sin_ = (t & 1) ? sA : sB;
        float* sout = (t == 50) ? out_struct : ((t & 1) ? sB : sA);
        adam_step_k<<<dim3(BS * 64 / 256), blk, 0, stream>>>(sin_, sout, mB, vB, probs,
                                                             bc1inv, bc2inv);
    }
}

// Round 2
// 942.437 us; speedup vs baseline: 1.5721x; 1.5721x over previous
//
#include <hip/hip_runtime.h>
#include <cmath>

static constexpr int Bb = 4, Ss = 1024, Ee = 768, Hh = 8, HDd = 96;
static constexpr int BS = Bb * Ss;  // 4096 rows

typedef __attribute__((ext_vector_type(8))) short short8v;  // 8 x bf16 bits (4 VGPRs)
typedef __attribute__((ext_vector_type(4))) float f32x4;

// fp32 -> bf16 bits, round-to-nearest-even
__device__ __forceinline__ ushort f2b(float f) {
    unsigned u = __float_as_uint(f);
    unsigned r = (u + 0x7FFFu + ((u >> 16) & 1u)) >> 16;
    return (ushort)r;
}
__device__ __forceinline__ float b2f(ushort b) {
    return __uint_as_float(((unsigned)b) << 16);
}

__device__ __forceinline__ void gload16(const void* g, void* l) {
    __builtin_amdgcn_global_load_lds(
        (const __attribute__((address_space(1))) unsigned int*)g,
        (__attribute__((address_space(3))) unsigned int*)l, 16, 0, 0);
}

// ---------------- fp32 -> bf16 convert (row-major, no transpose) ----------------
__global__ __launch_bounds__(256) void cvt_bf16_k(
    const float* __restrict__ in, ushort* __restrict__ out, int n)
{
    const int i = (blockIdx.x * 256 + threadIdx.x) * 4;
    if (i >= n) return;
    const float4 v = *reinterpret_cast<const float4*>(in + i);
    ushort4 o;
    o.x = f2b(v.x); o.y = f2b(v.y); o.z = f2b(v.z); o.w = f2b(v.w);
    *reinterpret_cast<ushort4*>(out + i) = o;
}

// ---------------- W[K,N] fp32 -> Wt[N,K] bf16 (tiled transpose-convert) ----------------
__global__ __launch_bounds__(256) void tcvt_k(
    const float* __restrict__ W, ushort* __restrict__ Wt, int K, int N)
{
    __shared__ float tile[64][65];
    const int nb = blockIdx.x * 64, kb = blockIdx.y * 64;
    const int t = threadIdx.x;
    {
        const int nn = t & 63, k4 = t >> 6;  // k4: 0..3
#pragma unroll
        for (int r = 0; r < 16; ++r) {
            const int kk = k4 * 16 + r;
            tile[kk][nn] = W[(size_t)(kb + kk) * N + nb + nn];
        }
    }
    __syncthreads();
    {
        const int kk = t & 63, n4 = t >> 6;
#pragma unroll
        for (int r = 0; r < 16; ++r) {
            const int nn = n4 * 16 + r;
            Wt[(size_t)(nb + nn) * K + kb + kk] = f2b(tile[kk][nn]);
        }
    }
}

// ---------------- bf16 MFMA GEMM: C = act(A[M,K] @ Wt[N,K]^T + bias[N]) ----------------
// 128x128 tile, BK=32, 256 threads = 4 waves (2x2 of 64x64), 16x16x32 MFMA,
// global_load_lds(16B) staging, m97 2-barrier structure.
template <int RELU, int WF32, int WB16>
__global__ __launch_bounds__(256) void gemm_bf16_k(
    const ushort* __restrict__ A, const ushort* __restrict__ Bt,
    const float* __restrict__ bias,
    float* __restrict__ Cf, ushort* __restrict__ Cb,
    int M, int N, int K)
{
    __shared__ ushort As[128 * 32];
    __shared__ ushort Bs[128 * 32];
    const int t = threadIdx.x, lane = t & 63, wid = t >> 6;
    const int bm = blockIdx.y, bn = blockIdx.x;
    const int wr = wid >> 1, wc = wid & 1;  // wave -> 64x64 quadrant

    // staging: wave wid covers tile rows [wid*32, wid*32+32); 2 issues of 16 rows.
    const int r0 = wid * 32 + (lane >> 2);     // issue-0 row (lane>>2 in 0..15)
    const int sc = (lane & 3) * 8;             // ushort offset within 32-elem K-window
    const ushort* Ag0 = A  + (size_t)(bm * 128 + r0) * K + sc;
    const ushort* Ag1 = Ag0 + (size_t)16 * K;
    const ushort* Bg0 = Bt + (size_t)(bn * 128 + r0) * K + sc;
    const ushort* Bg1 = Bg0 + (size_t)16 * K;
    char* AsB = (char*)As + wid * 2048;
    char* BsB = (char*)Bs + wid * 2048;

    f32x4 acc[4][4];
#pragma unroll
    for (int m = 0; m < 4; ++m)
#pragma unroll
        for (int n = 0; n < 4; ++n) acc[m][n] = (f32x4){0.f, 0.f, 0.f, 0.f};

    const int fr = lane & 15, ks = (lane >> 4) * 8;  // fragment row / k-slice

    for (int k0 = 0; k0 < K; k0 += 32) {
        __syncthreads();  // previous iteration's ds_reads done before overwrite
        gload16(Ag0 + k0, AsB);
        gload16(Ag1 + k0, AsB + 1024);
        gload16(Bg0 + k0, BsB);
        gload16(Bg1 + k0, BsB + 1024);
        __syncthreads();  // compiler drains vmcnt before barrier -> LDS ready

        short8v a[4], b[4];
#pragma unroll
        for (int m = 0; m < 4; ++m)
            a[m] = *reinterpret_cast<const short8v*>(&As[(wr * 64 + m * 16 + fr) * 32 + ks]);
#pragma unroll
        for (int n = 0; n < 4; ++n)
            b[n] = *reinterpret_cast<const short8v*>(&Bs[(wc * 64 + n * 16 + fr) * 32 + ks]);
#pragma unroll
        for (int m = 0; m < 4; ++m)
#pragma unroll
            for (int n = 0; n < 4; ++n)
                acc[m][n] = __builtin_amdgcn_mfma_f32_16x16x32_bf16(a[m], b[n], acc[m][n], 0, 0, 0);
    }

    // epilogue: C/D layout col=lane&15, row=(lane>>4)*4+reg
    const int col0 = bn * 128 + wc * 64 + (lane & 15);
    const int rw0  = bm * 128 + wr * 64 + (lane >> 4) * 4;
#pragma unroll
    for (int n = 0; n < 4; ++n) {
        const int col = col0 + n * 16;
        const float bv = bias[col];
#pragma unroll
        for (int m = 0; m < 4; ++m) {
            const f32x4 v = acc[m][n];
#pragma unroll
            for (int r = 0; r < 4; ++r) {
                const int row = rw0 + m * 16 + r;
                float val = v[r] + bv;
                if (RELU) val = fmaxf(val, 0.f);
                if (WF32) Cf[(size_t)row * N + col] = val;
                if (WB16) Cb[(size_t)row * N + col] = f2b(val);
            }
        }
    }
}

// ---------------- attention over the BATCH axis (bf16 in/out, fp32 math) ----------------
__global__ __launch_bounds__(256) void attn_batch_k(
    const ushort* __restrict__ q, const ushort* __restrict__ k,
    const ushort* __restrict__ v, ushort* __restrict__ ao)
{
    const int idx = blockIdx.x * 256 + threadIdx.x;
    if (idx >= Ss * Hh) return;
    const int s = idx / Hh, h = idx - s * Hh;
    const size_t base    = (size_t)s * Ee + (size_t)h * HDd;
    const size_t bstride = (size_t)Ss * Ee;

    float sc[4][4] = {};
    for (int d = 0; d < HDd; ++d) {
        float qq[4], kk4[4];
#pragma unroll
        for (int b = 0; b < 4; ++b) qq[b] = b2f(q[b * bstride + base + d]);
#pragma unroll
        for (int c = 0; c < 4; ++c) kk4[c] = b2f(k[c * bstride + base + d]);
#pragma unroll
        for (int b = 0; b < 4; ++b)
#pragma unroll
            for (int c = 0; c < 4; ++c)
                sc[b][c] = fmaf(qq[b], kk4[c], sc[b][c]);
    }
    const float scale = 0.10206207261596577f;  // 1/sqrt(96)
    float at[4][4];
#pragma unroll
    for (int b = 0; b < 4; ++b) {
        float mx = sc[b][0];
#pragma unroll
        for (int c = 1; c < 4; ++c) mx = fmaxf(mx, sc[b][c]);
        float sum = 0.f;
#pragma unroll
        for (int c = 0; c < 4; ++c) { at[b][c] = expf((sc[b][c] - mx) * scale); sum += at[b][c]; }
        const float inv = 1.f / sum;
#pragma unroll
        for (int c = 0; c < 4; ++c) at[b][c] *= inv;
    }
    for (int d = 0; d < HDd; ++d) {
        float vv[4];
#pragma unroll
        for (int c = 0; c < 4; ++c) vv[c] = b2f(v[c * bstride + base + d]);
#pragma unroll
        for (int b = 0; b < 4; ++b) {
            float o = 0.f;
#pragma unroll
            for (int c = 0; c < 4; ++c) o = fmaf(at[b][c], vv[c], o);
            ao[b * bstride + base + d] = f2b(o);
        }
    }
}

// ---------------- probs = m1[BS,384] @ w2[384,1] + b2 : one wave per row ----------------
__global__ __launch_bounds__(256) void mlp2_probs_k(
    const float* __restrict__ m1, const float* __restrict__ w2,
    const float* __restrict__ b2, float* __restrict__ probs)
{
    const int gid  = blockIdx.x * 256 + threadIdx.x;
    const int row  = gid >> 6, lane = gid & 63;
    if (row >= BS) return;
    float acc = 0.f;
    for (int kk = lane; kk < 384; kk += 64)
        acc = fmaf(m1[(size_t)row * 384 + kk], w2[kk], acc);
#pragma unroll
    for (int off = 32; off > 0; off >>= 1) acc += __shfl_down(acc, off, 64);
    if (lane == 0) probs[row] = acc + b2[0];
}

// ---------------- ba = r1[BS,384] @ w2[384,3] + b2 : one wave per row ----------------
__global__ __launch_bounds__(256) void rb2_ba_k(
    const float* __restrict__ r1, const float* __restrict__ w2,
    const float* __restrict__ b2, float* __restrict__ ba)
{
    const int gid  = blockIdx.x * 256 + threadIdx.x;
    const int row  = gid >> 6, lane = gid & 63;
    if (row >= BS) return;
    float a0 = 0.f, a1 = 0.f, a2 = 0.f;
    for (int kk = lane; kk < 384; kk += 64) {
        const float r = r1[(size_t)row * 384 + kk];
        a0 = fmaf(r, w2[kk * 3 + 0], a0);
        a1 = fmaf(r, w2[kk * 3 + 1], a1);
        a2 = fmaf(r, w2[kk * 3 + 2], a2);
    }
#pragma unroll
    for (int off = 32; off > 0; off >>= 1) {
        a0 += __shfl_down(a0, off, 64);
        a1 += __shfl_down(a1, off, 64);
        a2 += __shfl_down(a2, off, 64);
    }
    if (lane == 0) {
        ba[(size_t)row * 3 + 0] = a0 + b2[0];
        ba[(size_t)row * 3 + 1] = a1 + b2[1];
        ba[(size_t)row * 3 + 2] = a2 + b2[2];
    }
}

// ---------------- contacts[b,i,j] = probs[b,i] (float4 fill) ----------------
__global__ __launch_bounds__(256) void contacts_k(
    const float* __restrict__ probs, float* __restrict__ out)
{
    const int f4 = blockIdx.x * 256 + threadIdx.x;
    if (f4 >= (Bb * Ss * Ss) / 4) return;
    const int row = f4 >> 8;
    const float p = probs[row];
    reinterpret_cast<float4*>(out)[f4] = make_float4(p, p, p, p);
}

// ---------------- steps + inclusive cumsum (Hillis-Steele), one block per b ----------------
__global__ __launch_bounds__(1024) void steps_cumsum_k(
    const float* __restrict__ ba, float* __restrict__ s0)
{
    const int b = blockIdx.x;
    const int i = threadIdx.x;
    const int row = b * Ss + i;
    const float phi = ba[(size_t)row * 3 + 0];
    const float psi = ba[(size_t)row * 3 + 1];
    const float cpsi = cosf(psi);
    float x = 3.8f * cosf(phi) * cpsi;
    float y = 3.8f * sinf(phi) * cpsi;
    float z = 3.8f * sinf(psi);
    if (i == 0) { x = 0.f; y = 0.f; z = 0.f; }
    __shared__ float sx[1024], sy[1024], sz[1024];
    sx[i] = x; sy[i] = y; sz[i] = z;
    for (int off = 1; off < 1024; off <<= 1) {
        __syncthreads();
        float ax = 0.f, ay = 0.f, az = 0.f;
        if (i >= off) { ax = sx[i - off]; ay = sy[i - off]; az = sz[i - off]; }
        __syncthreads();
        sx[i] += ax; sy[i] += ay; sz[i] += az;
    }
    s0[(size_t)row * 3 + 0] = sx[i];
    s0[(size_t)row * 3 + 1] = sy[i];
    s0[(size_t)row * 3 + 2] = sz[i];
}

// ---------------- one Adam step ----------------
__global__ __launch_bounds__(256) void adam_step_k(
    const float* __restrict__ sin_, float* __restrict__ sout,
    float* __restrict__ mbuf, float* __restrict__ vbuf,
    const float* __restrict__ probs, float bc1inv, float bc2inv)
{
    const int gid  = blockIdx.x * 256 + threadIdx.x;
    const int row  = gid >> 6, lane = gid & 63;
    if (row >= BS) return;
    const int jbase = (row >> 10) << 10;
    const float pi_ = probs[row];
    const float sx = sin_[(size_t)row * 3 + 0];
    const float sy = sin_[(size_t)row * 3 + 1];
    const float sz = sin_[(size_t)row * 3 + 2];
    float gx = 0.f, gy = 0.f, gz = 0.f;
    for (int j = lane; j < Ss; j += 64) {
        const int jd = jbase + j;
        const float tx = sin_[(size_t)jd * 3 + 0];
        const float ty = sin_[(size_t)jd * 3 + 1];
        const float tz = sin_[(size_t)jd * 3 + 2];
        const float dx = sx - tx, dy = sy - ty, dz = sz - tz;
        const float d2 = dx * dx + dy * dy + dz * dz;
        if (d2 > 0.f) {
            const float d  = sqrtf(d2);
            const float sg = (d > 8.f) ? 1.f : -1.f;
            const float w  = sg * (pi_ + probs[jd]) / d;
            gx = fmaf(w, dx, gx);
            gy = fmaf(w, dy, gy);
            gz = fmaf(w, dz, gz);
        }
    }
#pragma unroll
    for (int off = 32; off > 0; off >>= 1) {
        gx += __shfl_down(gx, off, 64);
        gy += __shfl_down(gy, off, 64);
        gz += __shfl_down(gz, off, 64);
    }
    if (lane == 0) {
        const float invN = 1.f / 4194304.f;
        float g[3] = { gx * invN, gy * invN, gz * invN };
        float scur[3] = { sx, sy, sz };
#pragma unroll
        for (int dI = 0; dI < 3; ++dI) {
            const size_t o = (size_t)row * 3 + dI;
            const float m = 0.9f * mbuf[o] + 0.1f * g[dI];
            const float v = 0.999f * vbuf[o] + 0.001f * g[dI] * g[dI];
            mbuf[o] = m; vbuf[o] = v;
            sout[o] = scur[dI] - 0.01f * (m * bc1inv) / (sqrtf(v * bc2inv) + 1e-8f);
        }
    }
}

extern "C" void kernel_launch(void* const* d_in, const int* in_sizes, int n_in,
                              void* d_out, int out_size, void* d_ws, size_t ws_size,
                              hipStream_t stream)
{
    const float* x     = (const float*)d_in[0];
    const float* bb_w1 = (const float*)d_in[1];
    const float* bb_b1 = (const float*)d_in[2];
    const float* bb_w2 = (const float*)d_in[3];
    const float* bb_b2 = (const float*)d_in[4];
    const float* sc_w1 = (const float*)d_in[5];
    const float* sc_b1 = (const float*)d_in[6];
    const float* sc_w2 = (const float*)d_in[7];
    const float* sc_b2 = (const float*)d_in[8];
    const float* wq = (const float*)d_in[9];  const float* bq = (const float*)d_in[10];
    const float* wk = (const float*)d_in[11]; const float* bk = (const float*)d_in[12];
    const float* wv = (const float*)d_in[13]; const float* bv = (const float*)d_in[14];
    const float* wo = (const float*)d_in[15]; const float* bo = (const float*)d_in[16];
    const float* mlp_w1 = (const float*)d_in[17]; const float* mlp_b1 = (const float*)d_in[18];
    const float* mlp_w2 = (const float*)d_in[19]; const float* mlp_b2 = (const float*)d_in[20];
    const float* rb_w1 = (const float*)d_in[21]; const float* rb_b1 = (const float*)d_in[22];
    const float* rb_w2 = (const float*)d_in[23]; const float* rb_b2 = (const float*)d_in[24];
    // rs_* dead in reference.

    float* out_backbone = (float*)d_out;                                  // [4096,768] f32
    float* out_side     = out_backbone + (size_t)BS * Ee;                 // [4096,768] f32
    float* out_contacts = out_side + (size_t)BS * Ee;                     // [4,1024,1024] f32
    float* out_struct   = out_contacts + (size_t)Bb * Ss * Ss;            // [4096,3] f32

    // ---- workspace layout (ushort units), ~38 MB total ----
    const size_t SLOT_E = (size_t)BS * Ee;      // 3,145,728 elems
    const size_t SLOT_H = (size_t)BS * 384;
    ushort* cur = (ushort*)d_ws;
    ushort* U0 = cur; cur += SLOT_E;            // xb -> m1(f32) -> r1(f32)
    ushort* U1 = cur; cur += SLOT_E;            // vb -> mb
    ushort* U2 = cur; cur += SLOT_E;            // backbone bf16 (live till rb1)
    ushort* U3 = cur; cur += SLOT_E;            // aob
    ushort* s1b = cur; cur += SLOT_H;           // sc1 out
    ushort* bb_w1t = cur; cur += 768 * 768;
    ushort* bb_w2t = cur; cur += 768 * 768;
    ushort* wqt    = cur; cur += 768 * 768;
    ushort* wkt    = cur; cur += 768 * 768;
    ushort* wvt    = cur; cur += 768 * 768;
    ushort* wot    = cur; cur += 768 * 768;
    ushort* sc_w1t = cur; cur += 768 * 384;
    ushort* sc_w2t = cur; cur += 768 * 384;
    ushort* mlp_w1t= cur; cur += 768 * 384;
    ushort* rb_w1t = cur; cur += 768 * 384;
    float* fcur = (float*)cur;
    float* probs = fcur; fcur += BS;
    float* ba    = fcur; fcur += 3 * BS;
    float* sA    = fcur; fcur += 3 * BS;
    float* sB    = fcur; fcur += 3 * BS;
    float* mB    = fcur; fcur += 3 * BS;
    float* vB    = fcur; fcur += 3 * BS;

    // scratch aliases inside d_out (dead until overwritten later):
    ushort* xb  = U0;
    ushort* h1b = (ushort*)out_side;            // dead after bb2; out_side written at sc2
    ushort* qb  = (ushort*)out_contacts;        // dead after attn; contacts written later
    ushort* kb  = qb + SLOT_E;
    ushort* vb  = U1;
    ushort* backboneb = U2;
    ushort* aob = U3;
    ushort* mb  = U1;                           // vb dead when wo writes mb
    float*  m1f = (float*)U0;                   // xb dead after v-projection
    float*  r1f = (float*)U0;                   // m1 dead after mlp2

    const dim3 blk(256);
    const dim3 gEE(768 / 128, BS / 128);        // N=768 tiles (6 x 32)
    const dim3 gEH(384 / 128, BS / 128);        // N=384 tiles (3 x 32)

    // ---- converts ----
    cvt_bf16_k<<<dim3((SLOT_E / 4 + 255) / 256), blk, 0, stream>>>(x, xb, (int)SLOT_E);
    tcvt_k<<<dim3(12, 12), blk, 0, stream>>>(bb_w1, bb_w1t, 768, 768);
    tcvt_k<<<dim3(12, 12), blk, 0, stream>>>(bb_w2, bb_w2t, 768, 768);
    tcvt_k<<<dim3(12, 12), blk, 0, stream>>>(wq, wqt, 768, 768);
    tcvt_k<<<dim3(12, 12), blk, 0, stream>>>(wk, wkt, 768, 768);
    tcvt_k<<<dim3(12, 12), blk, 0, stream>>>(wv, wvt, 768, 768);
    tcvt_k<<<dim3(12, 12), blk, 0, stream>>>(wo, wot, 768, 768);
    tcvt_k<<<dim3(6, 12), blk, 0, stream>>>(sc_w1, sc_w1t, 768, 384);
    tcvt_k<<<dim3(12, 6), blk, 0, stream>>>(sc_w2, sc_w2t, 384, 768);
    tcvt_k<<<dim3(6, 12), blk, 0, stream>>>(mlp_w1, mlp_w1t, 768, 384);
    tcvt_k<<<dim3(6, 12), blk, 0, stream>>>(rb_w1, rb_w1t, 768, 384);

    // ---- backbone / side ----
    gemm_bf16_k<1, 0, 1><<<gEE, blk, 0, stream>>>(xb, bb_w1t, bb_b1, nullptr, h1b, BS, 768, 768);
    gemm_bf16_k<0, 1, 1><<<gEE, blk, 0, stream>>>(h1b, bb_w2t, bb_b2, out_backbone, backboneb, BS, 768, 768);
    gemm_bf16_k<1, 0, 1><<<gEH, blk, 0, stream>>>(backboneb, sc_w1t, sc_b1, nullptr, s1b, BS, 384, 768);
    gemm_bf16_k<0, 1, 0><<<gEE, blk, 0, stream>>>(s1b, sc_w2t, sc_b2, out_side, nullptr, BS, 768, 384);

    // ---- contact predictor ----
    gemm_bf16_k<0, 0, 1><<<gEE, blk, 0, stream>>>(xb, wqt, bq, nullptr, qb, BS, 768, 768);
    gemm_bf16_k<0, 0, 1><<<gEE, blk, 0, stream>>>(xb, wkt, bk, nullptr, kb, BS, 768, 768);
    gemm_bf16_k<0, 0, 1><<<gEE, blk, 0, stream>>>(xb, wvt, bv, nullptr, vb, BS, 768, 768);
    attn_batch_k<<<dim3((Ss * Hh) / 256), blk, 0, stream>>>(qb, kb, vb, aob);
    gemm_bf16_k<0, 0, 1><<<gEE, blk, 0, stream>>>(aob, wot, bo, nullptr, mb, BS, 768, 768);
    gemm_bf16_k<1, 1, 0><<<gEH, blk, 0, stream>>>(mb, mlp_w1t, mlp_b1, m1f, nullptr, BS, 384, 768);
    mlp2_probs_k<<<dim3(BS * 64 / 256), blk, 0, stream>>>(m1f, mlp_w2, mlp_b2, probs);
    contacts_k<<<dim3(Bb * Ss * Ss / 4 / 256), blk, 0, stream>>>(probs, out_contacts);

    // ---- structure refiner ----
    gemm_bf16_k<1, 1, 0><<<gEH, blk, 0, stream>>>(backboneb, rb_w1t, rb_b1, r1f, nullptr, BS, 384, 768);
    rb2_ba_k<<<dim3(BS * 64 / 256), blk, 0, stream>>>(r1f, rb_w2, rb_b2, ba);
    steps_cumsum_k<<<dim3(Bb), dim3(1024), 0, stream>>>(ba, sA);

    // ---- 50 Adam steps ----
    hipMemsetAsync(mB, 0, (size_t)2 * 3 * BS * sizeof(float), stream);
    for (int t = 1; t <= 50; ++t) {
        const float bc1inv = (float)(1.0 / (1.0 - std::pow(0.9, (double)t)));
        const float bc2inv = (float)(1.0 / (1.0 - std::pow(0.999, (double)t)));
        const float* sin_ = (t & 1) ? sA : sB;
        float* sout = (t == 50) ? out_struct : ((t & 1) ? sB : sA);
        adam_step_k<<<dim3(BS * 64 / 256), blk, 0, stream>>>(sin_, sout, mB, vB, probs,
                                                             bc1inv, bc2inv);
    }
}